// Round 8
// baseline (149.485 us; speedup 1.0000x reference)
//
#include <hip/hip_runtime.h>

// ---------------------------------------------------------------------------
// Edge-conditioned kernel MLP, fully fused. R8 = R7 structure (flipped
// orientation C = W·h, pre-swizzled global_load_lds W staging, verified) with:
//   - 512-thread blocks (8 waves, fe=1): 16 waves/CU at same 64KB LDS
//   - tanh-GELU via __expf (HW v_exp) instead of erff (~30 VALU -> ~8)
//   - native __bf16 casts (v_cvt_pk_bf16_f32, RNE) instead of manual f2bf
//   - layer-3 outputs in 2 static registers (no sOut LDS region)
// ---------------------------------------------------------------------------

typedef __bf16 bf16x8 __attribute__((ext_vector_type(8)));
typedef __bf16 bf16x4 __attribute__((ext_vector_type(4)));
typedef float f32x4 __attribute__((ext_vector_type(4)));

#define N_EDGES 147456
#define TM 128            // edges per block = 8 waves x 16
#define NTHR 512

__device__ __forceinline__ unsigned short f2bf(float f) {
    unsigned u = __float_as_uint(f);
    u = u + 0x7FFFu + ((u >> 16) & 1u);   // RNE (prep kernel only)
    return (unsigned short)(u >> 16);
}
__device__ __forceinline__ float gelu_t(float x) {
    // tanh-form GELU == x * sigmoid(2z); dev from exact erf-GELU <= ~1e-3
    float z = 0.7978845608f * (x + 0.044715f * x * x * x);
    return x / (1.0f + __expf(-2.0f * z));
}
__device__ __forceinline__ void gl_lds16(const unsigned short* g, unsigned char* l) {
    __builtin_amdgcn_global_load_lds(
        (const __attribute__((address_space(1))) unsigned int*)g,
        (__attribute__((address_space(3))) unsigned int*)l, 16, 0, 0);
}

// Prep (R7 verbatim, verified): W^T bf16, PRE-SWIZZLED so linear-dest
// global_load_lds yields slot s at row n holding chunk (s ^ (n&7)).
__global__ void prep_weights(const float* __restrict__ W1,
                             const float* __restrict__ W2,
                             const float* __restrict__ W3,
                             unsigned short* __restrict__ ws) {
    int t = blockIdx.x * 256 + threadIdx.x;          // 163840 total
    if (t < 16384) {
        int k = t >> 7, n = t & 127;
        ws[n * 128 + (((k >> 3) ^ (n & 7)) << 3) + (k & 7)] = f2bf(W1[t]);
    } else if (t < 32768) {
        int j = t - 16384;
        int k = j >> 7, n = j & 127;
        ws[16384 + n * 128 + (((k >> 3) ^ (n & 7)) << 3) + (k & 7)] = f2bf(W2[j]);
    } else {
        int j = t - 32768;                           // j = k*1024 + n
        int k = j >> 10, n = j & 1023;
        int tile = n >> 7, nl = n & 127;
        ws[32768 + tile * 16384 + nl * 128 + (((k >> 3) ^ (nl & 7)) << 3) + (k & 7)]
            = f2bf(W3[j]);
    }
}

__global__ __launch_bounds__(NTHR, 2)
void fused_edge_mlp(const float* __restrict__ edge, const float* __restrict__ x,
                    const float* __restrict__ b1, const float* __restrict__ g1,
                    const float* __restrict__ be1,
                    const float* __restrict__ b2, const float* __restrict__ g2,
                    const float* __restrict__ be2,
                    const float* __restrict__ b3,
                    const unsigned short* __restrict__ wsW,
                    float* __restrict__ out) {
    // sA: bf16 [128 edge-rows][128 k], 256B/row, XOR-swizzled. edge->h1->h2.
    // Rows wave-private (wave w owns rows [w*16, w*16+16)).
    __shared__ __align__(16) unsigned char sA[TM * 256];       // 32 KB
    // sW: bf16 W^T tile [128 n][128 k], swizzled; filled by global_load_lds.
    __shared__ __align__(16) unsigned char sW[128 * 256];      // 32 KB

    const int t    = threadIdx.x;
    const int lane = t & 63;
    const int w    = t >> 6;          // 8 waves
    const int e0   = blockIdx.x * TM;
    const int erow = w * 16;          // wave's first local edge row (mult of 16)
    const int mrow = lane & 15;
    const int hi   = lane >> 4;
    const int swzl = (mrow & 7) << 4;

    // ---- W staging: async DMA, wave-uniform LDS base + lane*16 ----
    auto stageW = [&](const unsigned short* srcW) {
#pragma unroll
        for (int i = 0; i < 4; i++) {
            int base = w * 256 + i * 64;             // 2048 x 16B chunks total
            gl_lds16(srcW + (size_t)(base + lane) * 8, sW + (size_t)base * 16);
        }
    };

    // ---- MFMA pass (layers 1/2): C[n=128][e=16] += W(sW)^T . h(sA) ----
    auto runMM = [&](f32x4 (&acc)[8]) {
#pragma unroll
        for (int kk = 0; kk < 4; kk++) {
            int kb = (kk * 64 + hi * 16) ^ swzl;
            bf16x8 bB = *(const bf16x8*)(sA + (erow + mrow) * 256 + kb);
#pragma unroll
            for (int fn = 0; fn < 8; fn++) {
                bf16x8 a = *(const bf16x8*)(sW + (fn * 16 + mrow) * 256 + kb);
                acc[fn] = __builtin_amdgcn_mfma_f32_16x16x32_bf16(a, bB, acc[fn], 0, 0, 0);
            }
        }
    };
    // C/D: col(e-local-16) = mrow, feature n = fn*16 + hi*4 + rr.

    // ---- layer-3 MFMA with h2 B-frag cached in registers ----
    auto runMM3 = [&](f32x4 (&acc)[8], const bf16x8 (&bc)[4]) {
#pragma unroll
        for (int kk = 0; kk < 4; kk++) {
            int kb = (kk * 64 + hi * 16) ^ swzl;
#pragma unroll
            for (int fn = 0; fn < 8; fn++) {
                bf16x8 a = *(const bf16x8*)(sW + (fn * 16 + mrow) * 256 + kb);
                acc[fn] = __builtin_amdgcn_mfma_f32_16x16x32_bf16(a, bc[kk], acc[fn], 0, 0, 0);
            }
        }
    };

    f32x4 xq[2];                      // x[e][b*16 + hi*4 .. +4]

    // ---- LN + GELU per edge-col (R5 math, fe=1); h -> own sA row ----
    auto lnGelu = [&](f32x4 (&acc)[8], const float* bb, const float* gg,
                      const float* ee) {
        float hv[8][4];
        float s = 0.f, s2 = 0.f;
#pragma unroll
        for (int fn = 0; fn < 8; fn++) {
            f32x4 b4 = *(const f32x4*)(bb + fn * 16 + hi * 4);
#pragma unroll
            for (int rr = 0; rr < 4; rr++) {
                float v = acc[fn][rr] + b4[rr];
                hv[fn][rr] = v; s += v; s2 += v * v;
            }
        }
        s  += __shfl_xor(s, 16);  s  += __shfl_xor(s, 32);
        s2 += __shfl_xor(s2, 16); s2 += __shfl_xor(s2, 32);
        float mean = s * (1.0f / 128.0f);
        float rsv  = rsqrtf(s2 * (1.0f / 128.0f) - mean * mean + 1e-5f);
        int row = erow + mrow;                       // row&7 == mrow&7
#pragma unroll
        for (int fn = 0; fn < 8; fn++) {
            f32x4 g4 = *(const f32x4*)(gg + fn * 16 + hi * 4);
            f32x4 e4 = *(const f32x4*)(ee + fn * 16 + hi * 4);
            bf16x4 u;
#pragma unroll
            for (int rr = 0; rr < 4; rr++) {
                float f = (hv[fn][rr] - mean) * rsv * g4[rr] + e4[rr];
                u[rr] = (__bf16)gelu_t(f);           // v_cvt_pk_bf16_f32 (RNE)
            }
            *(bf16x4*)(sA + row * 256 + ((fn * 32 + hi * 8) ^ swzl)) = u;
        }
    };

    // ---- layer-3 GEMV (verified math, fe=1); results into 2 static regs ----
    f32x4 voutA, voutB;               // chunks 2*hi and 2*hi+1
    auto gemv = [&](f32x4 (&acc)[8], int c) {        // c is compile-time const
        f32x4 b3q[8];
#pragma unroll
        for (int fn = 0; fn < 8; fn++)
            b3q[fn] = *(const f32x4*)(b3 + c * 128 + fn * 16 + hi * 4);
        f32x4 pv;
#pragma unroll
        for (int o = 0; o < 4; o++) {
            float p = 0.f;
#pragma unroll
            for (int rr = 0; rr < 4; rr++) {
                p += (acc[2*o][rr]   + b3q[2*o][rr])   * xq[0][rr];
                p += (acc[2*o+1][rr] + b3q[2*o+1][rr]) * xq[1][rr];
            }
            p += __shfl_xor(p, 16);                  // reduce over hi
            p += __shfl_xor(p, 32);
            pv[o] = p;
        }
        if (hi == (c >> 1)) {                        // folds at compile time
            if (c & 1) voutB = pv; else voutA = pv;
        }
    };

    // ================= prologue =================
    stageW(wsW);                                     // W1 DMA (overlaps below)
#pragma unroll
    for (int i = 0; i < 4; i++) {                    // edge -> sA (wave rows)
        int c = lane + i * 64;                       // 256 chunks of 8 floats
        int r = erow + (c >> 4), kg = c & 15;
        const float* src = edge + (size_t)(e0 + r) * 128 + kg * 8;
        float4 v0 = *(const float4*)src, v1 = *(const float4*)(src + 4);
        bf16x8 u;
        u[0] = (__bf16)v0.x; u[1] = (__bf16)v0.y; u[2] = (__bf16)v0.z; u[3] = (__bf16)v0.w;
        u[4] = (__bf16)v1.x; u[5] = (__bf16)v1.y; u[6] = (__bf16)v1.z; u[7] = (__bf16)v1.w;
        *(bf16x8*)(sA + r * 256 + ((kg * 16) ^ ((r & 7) << 4))) = u;
    }
#pragma unroll
    for (int b = 0; b < 2; b++)
        xq[b] = *(const f32x4*)(
            x + (size_t)(e0 + erow + mrow) * 32 + b * 16 + hi * 4);
    __syncthreads();                                 // W1 in LDS (vmcnt drained)

    f32x4 acc[8];
    const f32x4 zz = {0.f, 0.f, 0.f, 0.f};

    // ================= layer 1 =================
#pragma unroll
    for (int j = 0; j < 8; j++) acc[j] = zz;
    runMM(acc);                       // reads sW(W1) + own sA row
    __syncthreads();                  // all waves done reading sW(W1)
    stageW(wsW + 16384);              // W2 DMA (overlaps lnGelu VALU)
    lnGelu(acc, b1, g1, be1);         // own sA rows <- h1
    __syncthreads();                  // W2 ready

    // ================= layer 2 =================
#pragma unroll
    for (int j = 0; j < 8; j++) acc[j] = zz;
    runMM(acc);
    __syncthreads();
    stageW(wsW + 32768);              // W3 chunk 0 DMA
    lnGelu(acc, b2, g2, be2);         // own sA rows <- h2
    __syncthreads();                  // W3c0 ready

    // ---- cache h2 B-frag in registers ----
    bf16x8 bc[4];
#pragma unroll
    for (int kk = 0; kk < 4; kk++) {
        int kb = (kk * 64 + hi * 16) ^ swzl;
        bc[kk] = *(const bf16x8*)(sA + (erow + mrow) * 256 + kb);
    }

    // ================= layer 3: 8 chunks of 128 features =================
#pragma unroll
    for (int c = 0; c < 8; c++) {
#pragma unroll
        for (int j = 0; j < 8; j++) acc[j] = zz;
        runMM3(acc, bc);              // reads sW(W3c) + bc regs
        __syncthreads();              // sW(W3c) reads done
        if (c < 7) stageW(wsW + 32768 + (size_t)(c + 1) * 16384);  // async DMA
        gemv(acc, c);                 // VALU + shfl (under DMA shadow)
        if (c < 7) __syncthreads();   // DMA drained
    }

    // ================= epilogue: coalesced register stores =================
    {
        size_t e = (size_t)(e0 + erow + mrow);
        *(f32x4*)(out + e * 32 + hi * 8)     = voutA;
        *(f32x4*)(out + e * 32 + hi * 8 + 4) = voutB;
    }
}

extern "C" void kernel_launch(void* const* d_in, const int* in_sizes, int n_in,
                              void* d_out, int out_size, void* d_ws, size_t ws_size,
                              hipStream_t stream) {
    const float* x    = (const float*)d_in[0];
    const float* edge = (const float*)d_in[1];
    const float* W1   = (const float*)d_in[2];
    const float* b1   = (const float*)d_in[3];
    const float* g1   = (const float*)d_in[4];
    const float* be1  = (const float*)d_in[5];
    const float* W2   = (const float*)d_in[6];
    const float* b2   = (const float*)d_in[7];
    const float* g2   = (const float*)d_in[8];
    const float* be2  = (const float*)d_in[9];
    const float* W3   = (const float*)d_in[10];
    const float* b3   = (const float*)d_in[11];
    unsigned short* wsW = (unsigned short*)d_ws;     // 320 KB pre-swizzled W^T bf16
    float* outp = (float*)d_out;

    prep_weights<<<640, 256, 0, stream>>>(W1, W2, W3, wsW);
    fused_edge_mlp<<<N_EDGES / TM, NTHR, 0, stream>>>(
        edge, x, b1, g1, be1, b2, g2, be2, b3, wsW, outp);
}

// Round 10
// 107.812 us; speedup vs baseline: 1.3865x; 1.3865x over previous
//
#include <hip/hip_runtime.h>

// ---------------------------------------------------------------------------
// Edge-conditioned kernel MLP, fully fused. R10 = R9 resubmitted verbatim
// (R9 bench died on infra before execution):
//   - __launch_bounds__(512, 4): 4 waves/EU -> TRUE 2 blocks/CU (16 waves/CU).
//     (R8's (512,2) silently meant 1 block/CU - that's why occupancy stuck.)
//   - double-buffered W3 staging: after bc caching sA is dead, so layer 3
//     ping-pongs W chunks between sW and sA; DMA issued one full chunk ahead,
//     ONE barrier per chunk, drain ~free.
// Math/layouts identical to R8 (verified, absmax 0.125).
// ---------------------------------------------------------------------------

typedef __bf16 bf16x8 __attribute__((ext_vector_type(8)));
typedef __bf16 bf16x4 __attribute__((ext_vector_type(4)));
typedef float f32x4 __attribute__((ext_vector_type(4)));

#define N_EDGES 147456
#define TM 128            // edges per block = 8 waves x 16
#define NTHR 512

__device__ __forceinline__ unsigned short f2bf(float f) {
    unsigned u = __float_as_uint(f);
    u = u + 0x7FFFu + ((u >> 16) & 1u);   // RNE (prep kernel only)
    return (unsigned short)(u >> 16);
}
__device__ __forceinline__ float gelu_t(float x) {
    float z = 0.7978845608f * (x + 0.044715f * x * x * x);
    return x / (1.0f + __expf(-2.0f * z));   // tanh-GELU, dev <= ~1e-3
}
__device__ __forceinline__ void gl_lds16(const unsigned short* g, unsigned char* l) {
    __builtin_amdgcn_global_load_lds(
        (const __attribute__((address_space(1))) unsigned int*)g,
        (__attribute__((address_space(3))) unsigned int*)l, 16, 0, 0);
}

// Prep (verified R7/R8): W^T bf16, PRE-SWIZZLED so linear-dest global_load_lds
// yields slot s at row n holding chunk (s ^ (n&7)).
__global__ void prep_weights(const float* __restrict__ W1,
                             const float* __restrict__ W2,
                             const float* __restrict__ W3,
                             unsigned short* __restrict__ ws) {
    int t = blockIdx.x * 256 + threadIdx.x;          // 163840 total
    if (t < 16384) {
        int k = t >> 7, n = t & 127;
        ws[n * 128 + (((k >> 3) ^ (n & 7)) << 3) + (k & 7)] = f2bf(W1[t]);
    } else if (t < 32768) {
        int j = t - 16384;
        int k = j >> 7, n = j & 127;
        ws[16384 + n * 128 + (((k >> 3) ^ (n & 7)) << 3) + (k & 7)] = f2bf(W2[j]);
    } else {
        int j = t - 32768;                           // j = k*1024 + n
        int k = j >> 10, n = j & 1023;
        int tile = n >> 7, nl = n & 127;
        ws[32768 + tile * 16384 + nl * 128 + (((k >> 3) ^ (nl & 7)) << 3) + (k & 7)]
            = f2bf(W3[j]);
    }
}

__global__ __launch_bounds__(NTHR, 4)
void fused_edge_mlp(const float* __restrict__ edge, const float* __restrict__ x,
                    const float* __restrict__ b1, const float* __restrict__ g1,
                    const float* __restrict__ be1,
                    const float* __restrict__ b2, const float* __restrict__ g2,
                    const float* __restrict__ be2,
                    const float* __restrict__ b3,
                    const unsigned short* __restrict__ wsW,
                    float* __restrict__ out) {
    // sA: bf16 [128 rows][128 k], XOR-swizzled. edge->h1->h2; then W buf B.
    __shared__ __align__(16) unsigned char sA[TM * 256];       // 32 KB
    // sW: bf16 W^T tile [128 n][128 k], swizzled; W buf A.
    __shared__ __align__(16) unsigned char sW[128 * 256];      // 32 KB

    const int t    = threadIdx.x;
    const int lane = t & 63;
    const int w    = t >> 6;          // 8 waves
    const int e0   = blockIdx.x * TM;
    const int erow = w * 16;          // wave's edge rows [erow, erow+16)
    const int mrow = lane & 15;
    const int hi   = lane >> 4;
    const int swzl = (mrow & 7) << 4;

    // ---- W staging: async DMA into dst; wave w covers rows [w*16,w*16+16) ----
    auto stageW = [&](const unsigned short* srcW, unsigned char* dst) {
#pragma unroll
        for (int i = 0; i < 4; i++) {
            int base = w * 256 + i * 64;             // 2048 x 16B chunks total
            gl_lds16(srcW + (size_t)(base + lane) * 8, dst + (size_t)base * 16);
        }
    };

    // ---- MFMA pass (layers 1/2): C[n=128][e=16] += W(sW)^T . h(sA) ----
    auto runMM = [&](f32x4 (&acc)[8]) {
#pragma unroll
        for (int kk = 0; kk < 4; kk++) {
            int kb = (kk * 64 + hi * 16) ^ swzl;
            bf16x8 bB = *(const bf16x8*)(sA + (erow + mrow) * 256 + kb);
#pragma unroll
            for (int fn = 0; fn < 8; fn++) {
                bf16x8 a = *(const bf16x8*)(sW + (fn * 16 + mrow) * 256 + kb);
                acc[fn] = __builtin_amdgcn_mfma_f32_16x16x32_bf16(a, bB, acc[fn], 0, 0, 0);
            }
        }
    };
    // C/D: col(e-local-16) = mrow, feature n = fn*16 + hi*4 + rr.

    // ---- layer-3 MFMA from arbitrary W buffer, h2 cached in bc regs ----
    auto runMM3 = [&](f32x4 (&acc)[8], const bf16x8 (&bc)[4],
                      const unsigned char* wbuf) {
#pragma unroll
        for (int kk = 0; kk < 4; kk++) {
            int kb = (kk * 64 + hi * 16) ^ swzl;
#pragma unroll
            for (int fn = 0; fn < 8; fn++) {
                bf16x8 a = *(const bf16x8*)(wbuf + (fn * 16 + mrow) * 256 + kb);
                acc[fn] = __builtin_amdgcn_mfma_f32_16x16x32_bf16(a, bc[kk], acc[fn], 0, 0, 0);
            }
        }
    };

    f32x4 xq[2];                      // x[e][b*16 + hi*4 .. +4]

    // ---- LN + GELU per edge-col (verified); h -> own sA row ----
    auto lnGelu = [&](f32x4 (&acc)[8], const float* bb, const float* gg,
                      const float* ee) {
        float hv[8][4];
        float s = 0.f, s2 = 0.f;
#pragma unroll
        for (int fn = 0; fn < 8; fn++) {
            f32x4 b4 = *(const f32x4*)(bb + fn * 16 + hi * 4);
#pragma unroll
            for (int rr = 0; rr < 4; rr++) {
                float v = acc[fn][rr] + b4[rr];
                hv[fn][rr] = v; s += v; s2 += v * v;
            }
        }
        s  += __shfl_xor(s, 16);  s  += __shfl_xor(s, 32);
        s2 += __shfl_xor(s2, 16); s2 += __shfl_xor(s2, 32);
        float mean = s * (1.0f / 128.0f);
        float rsv  = rsqrtf(s2 * (1.0f / 128.0f) - mean * mean + 1e-5f);
        int row = erow + mrow;                       // row&7 == mrow&7
#pragma unroll
        for (int fn = 0; fn < 8; fn++) {
            f32x4 g4 = *(const f32x4*)(gg + fn * 16 + hi * 4);
            f32x4 e4 = *(const f32x4*)(ee + fn * 16 + hi * 4);
            bf16x4 u;
#pragma unroll
            for (int rr = 0; rr < 4; rr++) {
                float f = (hv[fn][rr] - mean) * rsv * g4[rr] + e4[rr];
                u[rr] = (__bf16)gelu_t(f);           // v_cvt_pk_bf16_f32 (RNE)
            }
            *(bf16x4*)(sA + row * 256 + ((fn * 32 + hi * 8) ^ swzl)) = u;
        }
    };

    // ---- layer-3 GEMV (verified); results into 2 static regs ----
    f32x4 voutA, voutB;               // chunks 2*hi and 2*hi+1
    auto gemv = [&](f32x4 (&acc)[8], int c) {        // c compile-time const
        f32x4 b3q[8];
#pragma unroll
        for (int fn = 0; fn < 8; fn++)
            b3q[fn] = *(const f32x4*)(b3 + c * 128 + fn * 16 + hi * 4);
        f32x4 pv;
#pragma unroll
        for (int o = 0; o < 4; o++) {
            float p = 0.f;
#pragma unroll
            for (int rr = 0; rr < 4; rr++) {
                p += (acc[2*o][rr]   + b3q[2*o][rr])   * xq[0][rr];
                p += (acc[2*o+1][rr] + b3q[2*o+1][rr]) * xq[1][rr];
            }
            p += __shfl_xor(p, 16);                  // reduce over hi
            p += __shfl_xor(p, 32);
            pv[o] = p;
        }
        if (hi == (c >> 1)) {                        // folds at compile time
            if (c & 1) voutB = pv; else voutA = pv;
        }
    };

    // ================= prologue =================
    stageW(wsW, sW);                                 // W1 DMA (overlaps below)
#pragma unroll
    for (int i = 0; i < 4; i++) {                    // edge -> sA (wave rows)
        int c = lane + i * 64;                       // 256 chunks of 8 floats
        int r = erow + (c >> 4), kg = c & 15;
        const float* src = edge + (size_t)(e0 + r) * 128 + kg * 8;
        float4 v0 = *(const float4*)src, v1 = *(const float4*)(src + 4);
        bf16x8 u;
        u[0] = (__bf16)v0.x; u[1] = (__bf16)v0.y; u[2] = (__bf16)v0.z; u[3] = (__bf16)v0.w;
        u[4] = (__bf16)v1.x; u[5] = (__bf16)v1.y; u[6] = (__bf16)v1.z; u[7] = (__bf16)v1.w;
        *(bf16x8*)(sA + r * 256 + ((kg * 16) ^ ((r & 7) << 4))) = u;
    }
#pragma unroll
    for (int b = 0; b < 2; b++)
        xq[b] = *(const f32x4*)(
            x + (size_t)(e0 + erow + mrow) * 32 + b * 16 + hi * 4);
    __syncthreads();                                 // W1 in LDS

    f32x4 acc[8];
    const f32x4 zz = {0.f, 0.f, 0.f, 0.f};

    // ================= layer 1 =================
#pragma unroll
    for (int j = 0; j < 8; j++) acc[j] = zz;
    runMM(acc);                       // reads sW(W1) + own sA row
    __syncthreads();                  // all waves done reading sW(W1)
    stageW(wsW + 16384, sW);          // W2 DMA (overlaps lnGelu VALU)
    lnGelu(acc, b1, g1, be1);         // own sA rows <- h1
    __syncthreads();                  // W2 ready

    // ================= layer 2 =================
#pragma unroll
    for (int j = 0; j < 8; j++) acc[j] = zz;
    runMM(acc);
    __syncthreads();
    stageW(wsW + 32768, sW);          // W3 chunk 0 DMA
    lnGelu(acc, b2, g2, be2);         // own sA rows <- h2
    __syncthreads();                  // W3c0 ready; h2 in sA

    // ---- cache h2 B-frag in regs; then sA becomes W buffer B ----
    bf16x8 bc[4];
#pragma unroll
    for (int kk = 0; kk < 4; kk++) {
        int kb = (kk * 64 + hi * 16) ^ swzl;
        bc[kk] = *(const bf16x8*)(sA + (erow + mrow) * 256 + kb);
    }
    __syncthreads();                  // drains lgkm: bc reads done -> sA free
    stageW(wsW + 32768 + 16384, sA);  // W3 chunk 1 DMA -> sA (full chunk ahead)

    // ================= layer 3: 8 chunks, ping-pong sW/sA =================
#pragma unroll
    for (int c = 0; c < 8; c++) {
#pragma unroll
        for (int j = 0; j < 8; j++) acc[j] = zz;
        runMM3(acc, bc, (c & 1) ? sA : sW);   // read current buffer
        gemv(acc, c);                         // regs + shfl only
        if (c < 7) {
            __syncthreads();          // drain own vmcnt (c+1 landed long ago);
                                      // all waves done reading buf[c&1]
            if (c < 6)                // DMA c+2 into the buffer just freed
                stageW(wsW + 32768 + (size_t)(c + 2) * 16384,
                       (c & 1) ? sA : sW);
        }
    }

    // ================= epilogue: coalesced register stores =================
    {
        size_t e = (size_t)(e0 + erow + mrow);
        *(f32x4*)(out + e * 32 + hi * 8)     = voutA;
        *(f32x4*)(out + e * 32 + hi * 8 + 4) = voutB;
    }
}

extern "C" void kernel_launch(void* const* d_in, const int* in_sizes, int n_in,
                              void* d_out, int out_size, void* d_ws, size_t ws_size,
                              hipStream_t stream) {
    const float* x    = (const float*)d_in[0];
    const float* edge = (const float*)d_in[1];
    const float* W1   = (const float*)d_in[2];
    const float* b1   = (const float*)d_in[3];
    const float* g1   = (const float*)d_in[4];
    const float* be1  = (const float*)d_in[5];
    const float* W2   = (const float*)d_in[6];
    const float* b2   = (const float*)d_in[7];
    const float* g2   = (const float*)d_in[8];
    const float* be2  = (const float*)d_in[9];
    const float* W3   = (const float*)d_in[10];
    const float* b3   = (const float*)d_in[11];
    unsigned short* wsW = (unsigned short*)d_ws;     // 320 KB pre-swizzled W^T bf16
    float* outp = (float*)d_out;

    prep_weights<<<640, 256, 0, stream>>>(W1, W2, W3, wsW);
    fused_edge_mlp<<<N_EDGES / TM, NTHR, 0, stream>>>(
        edge, x, b1, g1, be1, b2, g2, be2, b3, wsW, outp);
}